// Round 5
// baseline (28124.255 us; speedup 1.0000x reference)
//
#include <hip/hip_runtime.h>
#include <math.h>

// Problem constants (from reference)
#define T_STEPS 8192
#define INPUT   64
#define UNITS   1024
#define NMOD    4
#define LEAKY   0.9f

// 32 WGs per module, 32 columns per WG, 1024 threads (16 waves) per WG.
// Each half-wave (32 lanes) owns one column; lane q owns rows 4q+128g+e.
// Wave w additionally POLLS h-columns [64w, 64w+64) of its module and
// deposits them in LDS for all waves (dataflow consumption, no barrier).
#define K_WG        32
#define COLS_PER_WG 32
#define NWG         (NMOD * K_WG)   // 128 workgroups
#define WGSIZE      1024

// d_ws layout: hb[2][NMOD*UNITS] packed {tag:32 | float:32} entries (64 KB).
#define HB_ENTRIES (2 * NMOD * UNITS)

__global__ void init_ws_kernel(unsigned long long* __restrict__ hb) {
    int i = blockIdx.x * blockDim.x + threadIdx.x;
    if (i < HB_ENTRIES) hb[i] = 0ULL;   // tag 0 < any t in 1..T
}

// tanh via exp2 + rcp: ~1e-6 rel err, correct saturation at +/-large x.
__device__ __forceinline__ float tanh_fast(float x) {
    float e2x = __builtin_amdgcn_exp2f(x * 2.8853900817779268f); // 2*log2(e)
    float r   = __builtin_amdgcn_rcpf(e2x + 1.0f);
    return fmaf(-2.0f, r, 1.0f);
}

// Half-wave (32-lane) sum via DPP butterfly (verified R4).
// RESULT: lanes 31 and 63 hold their half-wave sums.
__device__ __forceinline__ float halfwave_reduce_to_hi(float acc) {
    acc += __int_as_float(__builtin_amdgcn_update_dpp(
        0, __float_as_int(acc), 0xB1, 0xF, 0xF, false));   // quad_perm [1,0,3,2]
    acc += __int_as_float(__builtin_amdgcn_update_dpp(
        0, __float_as_int(acc), 0x4E, 0xF, 0xF, false));   // quad_perm [2,3,0,1]
    acc += __int_as_float(__builtin_amdgcn_update_dpp(
        0, __float_as_int(acc), 0x141, 0xF, 0xF, false));  // row_half_mirror
    acc += __int_as_float(__builtin_amdgcn_update_dpp(
        0, __float_as_int(acc), 0x140, 0xF, 0xF, false));  // row_mirror
    acc += __int_as_float(__builtin_amdgcn_update_dpp(
        0, __float_as_int(acc), 0x142, 0xA, 0xF, false));  // row_bcast:15 -> rows 1,3
    return acc;   // valid at lanes 31 and 63
}

__global__ __launch_bounds__(WGSIZE, 1)
void reservoir_persist(const float* __restrict__ u,
                       const float* __restrict__ kern,
                       const float* __restrict__ rec,
                       const float* __restrict__ bias,
                       float* __restrict__ out,
                       unsigned long long* __restrict__ hb)
{
    const int wg   = blockIdx.x;            // 0..127
    // XCD-pair mapping: if dispatch round-robins XCD = blockIdx%8, module m's
    // 32 WGs land on XCDs {2m, 2m+1}. Correctness does not depend on this.
    const int m    = (wg & 7) >> 1;                  // module 0..3
    const int wgi  = ((wg >> 3) << 1) | (wg & 1);    // 0..31 within module
    const int tid  = threadIdx.x;
    const int w    = tid >> 6;              // wave 0..15
    const int lane = tid & 63;
    const int half = lane >> 5;             // 0/1: which column of this wave
    const int q    = lane & 31;             // position within half-wave

    const int c = wgi * COLS_PER_WG + w * 2 + half;  // column within module

    // Double-buffered h + per-wave-block ready flags. NO __syncthreads in the
    // main loop: any t-tagged hbuf data implies every wave of every WG of this
    // module has finished consuming h_{t-2} (h_t needs ALL columns, and each
    // wave publishes its columns only after consuming the previous step), so
    // buffer (t&1) is never overwritten while still being read.
    __shared__ __align__(16) float h_lds[2][UNITS];
    __shared__ int ready[2][16];

    // ---- one-time preload of weights into registers ----
    // lane q owns rows 4q + 128g + e (g=0..7, e=0..3)
    const float* recm = rec + (size_t)m * UNITS * UNITS;
    float r[32];
#pragma unroll
    for (int g = 0; g < 8; ++g)
#pragma unroll
        for (int e = 0; e < 4; ++e)
            r[4 * g + e] = recm[(size_t)(4 * q + 128 * g + e) * UNITS + c];

    const float* km = kern + (size_t)m * INPUT * UNITS;
    const float k0 = km[(size_t)q * UNITS + c];
    const float k1 = km[(size_t)(q + 32) * UNITS + c];
    const float bc = bias[m * UNITS + c];

    const float leak = LEAKY;
    const float omleak = 1.0f - LEAKY;

    h_lds[0][tid] = 0.0f;                   // h_0 = 0
    if (tid < 16) { ready[0][tid] = 0; ready[1][tid] = -1; }
    __syncthreads();                        // the only barrier

    const size_t modOff = (size_t)m * UNITS;
    float hprev = 0.0f;                     // this leader's own column value

    for (int t = 1; t <= T_STEPS; ++t) {
        const int pbR = (t - 1) & 1;        // buffer holding h_{t-1}
        const int pbW = t & 1;              // buffer to fill with h_t

        // u row for this step (tiny, L2-resident; hides under group-0 spin)
        const float u0 = u[(size_t)(t - 1) * INPUT + q];
        const float u1 = u[(size_t)(t - 1) * INPUT + q + 32];

        // ---- consume h_{t-1} group-by-group as blocks arrive ----
        const float4* __restrict__ h4 = reinterpret_cast<const float4*>(h_lds[pbR]);
        float a0 = 0.f, a1 = 0.f, a2 = 0.f, a3 = 0.f;
#pragma unroll
        for (int g = 0; g < 8; ++g) {
            while (__hip_atomic_load(&ready[pbR][2 * g], __ATOMIC_ACQUIRE,
                                     __HIP_MEMORY_SCOPE_WORKGROUP) != t - 1) {}
            while (__hip_atomic_load(&ready[pbR][2 * g + 1], __ATOMIC_ACQUIRE,
                                     __HIP_MEMORY_SCOPE_WORKGROUP) != t - 1) {}
            float4 hv = h4[32 * g + q];
            a0 = fmaf(r[4 * g + 0], hv.x, a0);
            a1 = fmaf(r[4 * g + 1], hv.y, a1);
            a2 = fmaf(r[4 * g + 2], hv.z, a2);
            a3 = fmaf(r[4 * g + 3], hv.w, a3);
        }
        float acc = (a0 + a1) + (a2 + a3);
        acc = fmaf(u0, k0, acc);
        acc = fmaf(u1, k1, acc);

        // ---- pure-VALU reduction; result at lanes 31 and 63 ----
        acc = halfwave_reduce_to_hi(acc);

        unsigned long long* hbW = hb + (size_t)pbW * (NMOD * UNITS) + modOff;

        // ---- publish this wave's two columns (leaders: lanes 31, 63) ----
        if (q == 31) {
            float hn = omleak * hprev + leak * tanh_fast(acc + bc);
            hprev = hn;
            unsigned long long pk =
                ((unsigned long long)(unsigned int)t << 32) |
                (unsigned long long)__float_as_uint(hn);
            __hip_atomic_store(&hbW[c], pk,
                               __ATOMIC_RELAXED, __HIP_MEMORY_SCOPE_AGENT);
        }

        // ---- poll this wave's own 64-column block of h_t ----
        unsigned long long* myent = hbW + 64 * w + lane;
        float hv;
        for (;;) {
            unsigned long long v = __hip_atomic_load(myent, __ATOMIC_RELAXED,
                                                     __HIP_MEMORY_SCOPE_AGENT);
            if (__all((int)((unsigned int)(v >> 32) == (unsigned int)t))) {
                hv = __uint_as_float((unsigned int)v);
                break;
            }
            __builtin_amdgcn_s_sleep(1);
        }

        // deposit block in LDS; release flag orders the 64-lane ds_write
        h_lds[pbW][64 * w + lane] = hv;
        if (lane == 0)
            __hip_atomic_store(&ready[pbW][w], t, __ATOMIC_RELEASE,
                               __HIP_MEMORY_SCOPE_WORKGROUP);

        // one designated WG per module writes the coalesced output row,
        // straight from poll registers (off the critical publish path)
        if (wgi == 0)
            out[(size_t)(t - 1) * (NMOD * UNITS) + modOff + 64 * w + lane] = hv;
    }
}

extern "C" void kernel_launch(void* const* d_in, const int* in_sizes, int n_in,
                              void* d_out, int out_size, void* d_ws, size_t ws_size,
                              hipStream_t stream) {
    const float* u    = (const float*)d_in[0];  // [1, 8192, 64]
    const float* kern = (const float*)d_in[1];  // [4, 64, 1024]
    const float* rec  = (const float*)d_in[2];  // [4, 1024, 1024]
    const float* bias = (const float*)d_in[3];  // [4, 1024]
    float* out = (float*)d_out;                 // [1, 8192, 4096] f32
    unsigned long long* hb = (unsigned long long*)d_ws;  // 64 KB packed h buffer

    hipLaunchKernelGGL(init_ws_kernel, dim3((HB_ENTRIES + 1023) / 1024), dim3(1024),
                       0, stream, hb);

    void* args[] = { (void*)&u, (void*)&kern, (void*)&rec, (void*)&bias,
                     (void*)&out, (void*)&hb };
    hipLaunchCooperativeKernel((const void*)reservoir_persist,
                               dim3(NWG), dim3(WGSIZE), args, 0, stream);
}

// Round 6
// 21655.739 us; speedup vs baseline: 1.2987x; 1.2987x over previous
//
#include <hip/hip_runtime.h>
#include <math.h>

// Problem constants (from reference)
#define T_STEPS 8192
#define INPUT   64
#define UNITS   1024
#define NMOD    4
#define LEAKY   0.9f

// Decomposition: 16 WGs per module; module = blockIdx%8 (residues 0..3, the
// rest exit) so with round-robin XCD dispatch each module's WGs share ONE XCD
// and exchange h through that XCD's L2 (fast path). Correctness does NOT
// depend on the mapping: a slow agent-scope (MALL) path backs it up.
// WG = 1024 threads = 16 waves; each 16-lane group owns one column
// (4 cols/wave, 64 cols/WG); lane p of a group owns rows 4p+64j+e.
#define K_WG        16
#define COLS_PER_WG 64
#define GRID        128
#define WGSIZE      1024

#define ENTRIES     (NMOD * UNITS)   // 4096 packed entries per buffer
#define FAST_TRIES  8

// d_ws layout: slow[2][ENTRIES] then fast[2][ENTRIES], 64-bit {tag|value}.
#define WS_ULL      (4 * ENTRIES)

__global__ void init_ws_kernel(unsigned long long* __restrict__ b) {
    int i = blockIdx.x * blockDim.x + threadIdx.x;
    if (i < WS_ULL) b[i] = 0ULL;     // tag 0 < any t in 1..T
}

// tanh via exp2 + rcp: ~1e-6 rel err, correct saturation (verified R4).
__device__ __forceinline__ float tanh_fast(float x) {
    float e2x = __builtin_amdgcn_exp2f(x * 2.8853900817779268f); // 2*log2(e)
    float r   = __builtin_amdgcn_rcpf(e2x + 1.0f);
    return fmaf(-2.0f, r, 1.0f);
}

// 16-lane (column-group) sum via DPP butterfly; ALL 16 lanes end with the sum.
// Steps verified in R4 (first 4 stages of the 32-lane reduce).
__device__ __forceinline__ float group16_reduce(float acc) {
    acc += __int_as_float(__builtin_amdgcn_update_dpp(
        0, __float_as_int(acc), 0xB1, 0xF, 0xF, false));   // quad_perm [1,0,3,2]
    acc += __int_as_float(__builtin_amdgcn_update_dpp(
        0, __float_as_int(acc), 0x4E, 0xF, 0xF, false));   // quad_perm [2,3,0,1]
    acc += __int_as_float(__builtin_amdgcn_update_dpp(
        0, __float_as_int(acc), 0x141, 0xF, 0xF, false));  // row_half_mirror
    acc += __int_as_float(__builtin_amdgcn_update_dpp(
        0, __float_as_int(acc), 0x140, 0xF, 0xF, false));  // row_mirror
    return acc;
}

// L1-bypass (sc0) 8-byte load: served coherently from the LOCAL XCD's L2.
// Same-XCD producers' plain stores become visible here at L2 latency.
__device__ __forceinline__ unsigned long long load_l2(
        const unsigned long long* p) {
    unsigned long long v;
    asm volatile("global_load_dwordx2 %0, %1, off sc0\n\t"
                 "s_waitcnt vmcnt(0)"
                 : "=v"(v) : "v"(p) : "memory");
    return v;
}

__global__ __launch_bounds__(WGSIZE, 1)
void reservoir_persist(const float* __restrict__ u,
                       const float* __restrict__ kern,
                       const float* __restrict__ rec,
                       const float* __restrict__ bias,
                       float* __restrict__ out,
                       unsigned long long* __restrict__ slow,
                       unsigned long long* __restrict__ fast)
{
    const int wg  = blockIdx.x;
    const int res = wg & 7;
    if (res >= NMOD) return;             // residues 4..7 idle
    const int m   = res;                 // module 0..3 (one XCD residue each)
    const int wgi = wg >> 3;             // 0..15 within module

    const int tid  = threadIdx.x;
    const int w    = tid >> 6;           // wave 0..15
    const int lane = tid & 63;
    const int g    = lane >> 4;          // column group 0..3 within wave
    const int p    = lane & 15;          // lane within group

    const int c = wgi * COLS_PER_WG + w * 4 + g;   // module-local column

    __shared__ __align__(16) float h_lds[2][UNITS];

    // ---- one-time preload of weights into registers ----
    // lane p owns rows 4p + 64j + e (j=0..15, e=0..3) of column c
    const float* recm = rec + (size_t)m * UNITS * UNITS;
    float r[64];
#pragma unroll
    for (int j = 0; j < 16; ++j)
#pragma unroll
        for (int e = 0; e < 4; ++e)
            r[4 * j + e] = recm[(size_t)(4 * p + 64 * j + e) * UNITS + c];

    const float* km = kern + (size_t)m * INPUT * UNITS;
    const float k0 = km[(size_t)(4 * p + 0) * UNITS + c];
    const float k1 = km[(size_t)(4 * p + 1) * UNITS + c];
    const float k2 = km[(size_t)(4 * p + 2) * UNITS + c];
    const float k3 = km[(size_t)(4 * p + 3) * UNITS + c];
    const float bc = bias[m * UNITS + c];

    const float leak = LEAKY, omleak = 1.0f - LEAKY;

    h_lds[0][tid] = 0.0f;                // h_0 = 0
    __syncthreads();

    const size_t modOff = (size_t)m * UNITS;
    float hprev = 0.0f;                  // leader's own column state

    for (int t = 1; t <= T_STEPS; ++t) {
        const int pbR = (t - 1) & 1;
        const int pbW = t & 1;

        // input row (16 lanes x float4 = 64 values; replicated per group)
        const float4 uq =
            reinterpret_cast<const float4*>(u + (size_t)(t - 1) * INPUT)[p];

        // ---- dot: 16x ds_read_b128 + 64 FMA per lane ----
        const float4* __restrict__ h4 =
            reinterpret_cast<const float4*>(h_lds[pbR]);
        float a0 = uq.x * k0, a1 = uq.y * k1, a2 = uq.z * k2, a3 = uq.w * k3;
#pragma unroll
        for (int j = 0; j < 16; ++j) {
            float4 hv4 = h4[p + 16 * j];
            a0 = fmaf(r[4 * j + 0], hv4.x, a0);
            a1 = fmaf(r[4 * j + 1], hv4.y, a1);
            a2 = fmaf(r[4 * j + 2], hv4.z, a2);
            a3 = fmaf(r[4 * j + 3], hv4.w, a3);
        }
        float acc = (a0 + a1) + (a2 + a3);
        acc = group16_reduce(acc);       // all 16 lanes hold column sum

        unsigned long long* fbW = fast + (size_t)pbW * ENTRIES + modOff;
        unsigned long long* sbW = slow + (size_t)pbW * ENTRIES + modOff;

        // ---- publish (leader lane of each column group) ----
        if (p == 0) {
            float hn = omleak * hprev + leak * tanh_fast(acc + bc);
            hprev = hn;
            unsigned long long pk =
                ((unsigned long long)(unsigned int)t << 32) |
                (unsigned long long)__float_as_uint(hn);
            // fast: plain store -> local XCD L2 (visible to sc0 loads there)
            __hip_atomic_store(&fbW[c], pk, __ATOMIC_RELAXED,
                               __HIP_MEMORY_SCOPE_WORKGROUP);
            // slow: agent store -> MALL (correct for any WG placement)
            __hip_atomic_store(&sbW[c], pk, __ATOMIC_RELAXED,
                               __HIP_MEMORY_SCOPE_AGENT);
        }

        // ---- poll own column: fast L2 path, then MALL fallback ----
        unsigned long long v = 0;
        bool ok = false;
        for (int it = 0; it < FAST_TRIES && !ok; ++it) {
            v = load_l2(&fbW[tid]);
            ok = ((unsigned int)(v >> 32) == (unsigned int)t);
        }
        while (!ok) {
            v = __hip_atomic_load(&sbW[tid], __ATOMIC_RELAXED,
                                  __HIP_MEMORY_SCOPE_AGENT);
            ok = ((unsigned int)(v >> 32) == (unsigned int)t);
            if (!ok) __builtin_amdgcn_s_sleep(1);
        }
        const float hv = __uint_as_float((unsigned int)v);
        h_lds[pbW][tid] = hv;

        // one WG per module writes the coalesced output row (off crit path)
        if (wgi == 0)
            out[(size_t)(t - 1) * (NMOD * UNITS) + modOff + tid] = hv;

        __syncthreads();   // h_lds[pbW] complete; pbR free for reuse at t+2
    }
}

extern "C" void kernel_launch(void* const* d_in, const int* in_sizes, int n_in,
                              void* d_out, int out_size, void* d_ws, size_t ws_size,
                              hipStream_t stream) {
    const float* u    = (const float*)d_in[0];  // [1, 8192, 64]
    const float* kern = (const float*)d_in[1];  // [4, 64, 1024]
    const float* rec  = (const float*)d_in[2];  // [4, 1024, 1024]
    const float* bias = (const float*)d_in[3];  // [4, 1024]
    float* out = (float*)d_out;                 // [1, 8192, 4096] f32

    unsigned long long* slow = (unsigned long long*)d_ws;              // 64 KB
    unsigned long long* fast = slow + 2 * ENTRIES;                     // 64 KB

    hipLaunchKernelGGL(init_ws_kernel, dim3((WS_ULL + 1023) / 1024), dim3(1024),
                       0, stream, slow);

    void* args[] = { (void*)&u, (void*)&kern, (void*)&rec, (void*)&bias,
                     (void*)&out, (void*)&slow, (void*)&fast };
    hipLaunchCooperativeKernel((const void*)reservoir_persist,
                               dim3(GRID), dim3(WGSIZE), args, 0, stream);
}

// Round 7
// 13274.814 us; speedup vs baseline: 2.1186x; 1.6313x over previous
//
#include <hip/hip_runtime.h>
#include <math.h>

// Problem constants (from reference)
#define T_STEPS 8192
#define INPUT   64
#define UNITS   1024
#define NMOD    4
#define LEAKY   0.9f

// Decomposition: 16 WGs per module; module = blockIdx%8 (residues 0..3, rest
// exit) so with round-robin XCD dispatch each module's WGs share ONE XCD and
// exchange h through that XCD's L2 (fast path, validated R6). A slow
// agent-scope (MALL) path backs it up for arbitrary placement.
//
// TRANSPOSED ownership (new in R7): lane l of EVERY wave owns column
// c = wgi*64 + l. Wave w handles h-rows [64w, 64w+64): it polls exactly those
// 64 h entries, stores them in a wave-private LDS slice, re-reads them as 16
// UNIFORM-ADDRESS float4 broadcasts, and FMAs against 64 register-pinned
// weights. No cross-lane reduction. Partials combine across waves in LDS;
// wave 0 finishes (bias+tanh+blend) and publishes the WG's 64 columns.
#define K_WG        16
#define COLS_PER_WG 64
#define GRID        128
#define WGSIZE      1024

#define ENTRIES     (NMOD * UNITS)   // 4096 packed entries per buffer
// d_ws layout: slow[2][ENTRIES] then fast[2][ENTRIES], 64-bit {tag|value}.
#define WS_ULL      (4 * ENTRIES)

__global__ void init_ws_kernel(unsigned long long* __restrict__ b) {
    int i = blockIdx.x * blockDim.x + threadIdx.x;
    if (i < WS_ULL) b[i] = 0ULL;     // tag 0 < any t in 1..T
}

// tanh via exp2 + rcp: ~1e-6 rel err, correct saturation (verified R4).
__device__ __forceinline__ float tanh_fast(float x) {
    float e2x = __builtin_amdgcn_exp2f(x * 2.8853900817779268f); // 2*log2(e)
    float r   = __builtin_amdgcn_rcpf(e2x + 1.0f);
    return fmaf(-2.0f, r, 1.0f);
}

// L1-bypass (sc0) 8-byte load: served coherently from the LOCAL XCD's L2.
__device__ __forceinline__ unsigned long long load_l2(
        const unsigned long long* p) {
    unsigned long long v;
    asm volatile("global_load_dwordx2 %0, %1, off sc0\n\t"
                 "s_waitcnt vmcnt(0)"
                 : "=v"(v) : "v"(p) : "memory");
    return v;
}

__global__ __launch_bounds__(WGSIZE, 1)
void reservoir_persist(const float* __restrict__ u,
                       const float* __restrict__ kern,
                       const float* __restrict__ rec,
                       const float* __restrict__ bias,
                       float* __restrict__ out,
                       unsigned long long* __restrict__ slow,
                       unsigned long long* __restrict__ fast)
{
    const int wg  = blockIdx.x;
    const int res = wg & 7;
    if (res >= NMOD) return;             // residues 4..7 idle
    const int m   = res;                 // module 0..3
    const int wgi = wg >> 3;             // 0..15 within module

    const int tid  = threadIdx.x;
    const int w    = tid >> 6;           // wave 0..15  (row-slice owner)
    const int lane = tid & 63;

    const int c       = wgi * COLS_PER_WG + lane;  // my column (module-local)
    const int rowBase = 64 * w;                    // my wave's h-row slice

    __shared__ __align__(16) float h_slice[16][64];  // wave-private row slices
    __shared__ float part[16][64];                   // partials [wave][col]

    // ---- one-time preload of weights into registers (PINNED) ----
    // r[4j+e] = rec[m][rowBase + 4j + e][c]   (coalesced across lanes)
    const float* recm = rec + (size_t)m * UNITS * UNITS;
    float r[64];
#pragma unroll
    for (int j = 0; j < 16; ++j)
#pragma unroll
        for (int e = 0; e < 4; ++e)
            r[4 * j + e] = recm[(size_t)(rowBase + 4 * j + e) * UNITS + c];
    // Pin: force all 64 weights live in VGPRs (R6 showed the compiler sinks
    // these loads into the loop otherwise -> VGPR_Count was only 52).
#pragma unroll
    for (int j = 0; j < 64; ++j) asm volatile("" : "+v"(r[j]));

    // input kernel slice: wave w folds u-rows [4w, 4w+4)
    const float* km = kern + (size_t)m * INPUT * UNITS;
    const float k0 = km[(size_t)(4 * w + 0) * UNITS + c];
    const float k1 = km[(size_t)(4 * w + 1) * UNITS + c];
    const float k2 = km[(size_t)(4 * w + 2) * UNITS + c];
    const float k3 = km[(size_t)(4 * w + 3) * UNITS + c];
    const float bc = bias[m * UNITS + c];

    const float leak = LEAKY, omleak = 1.0f - LEAKY;

    h_slice[w][lane] = 0.0f;             // h_0 = 0 (wave-private slice)
    float hprev = 0.0f;                  // combine wave: my column's h state
    __syncthreads();

    const size_t modOff = (size_t)m * UNITS;

    // u quad for step 1 (uses u[0]); uniform per wave
    float4 uq = *reinterpret_cast<const float4*>(u + 4 * w);

    for (int t = 1; t <= T_STEPS; ++t) {
        const int pbW = t & 1;

        // ---- FMA phase: rows [64w,64w+64) x my column, h via LDS broadcast
        const float4* __restrict__ hs4 =
            reinterpret_cast<const float4*>(h_slice[w]);
        float a0 = uq.x * k0, a1 = uq.y * k1, a2 = uq.z * k2, a3 = uq.w * k3;
#pragma unroll
        for (int j = 0; j < 16; ++j) {
            float4 hv4 = hs4[j];         // uniform address -> HW broadcast
            a0 = fmaf(r[4 * j + 0], hv4.x, a0);
            a1 = fmaf(r[4 * j + 1], hv4.y, a1);
            a2 = fmaf(r[4 * j + 2], hv4.z, a2);
            a3 = fmaf(r[4 * j + 3], hv4.w, a3);
        }
        part[w][lane] = (a0 + a1) + (a2 + a3);
        __syncthreads();   // all partials visible; the only barrier per step

        unsigned long long* fbW = fast + (size_t)pbW * ENTRIES + modOff;
        unsigned long long* sbW = slow + (size_t)pbW * ENTRIES + modOff;

        // ---- combine + publish (wave 0; lane l -> column c) ----
        // part reuse is race-free without a second barrier: any wave's
        // part-write for step t+1 requires its poll of step t, which requires
        // THIS publish, which happens after all part reads below.
        if (w == 0) {
            float s0 = part[0][lane] + part[1][lane];
            float s1 = part[2][lane] + part[3][lane];
            float s2 = part[4][lane] + part[5][lane];
            float s3 = part[6][lane] + part[7][lane];
#pragma unroll
            for (int ww = 8; ww < 16; ww += 4) {
                s0 += part[ww][lane];     s1 += part[ww + 1][lane];
                s2 += part[ww + 2][lane]; s3 += part[ww + 3][lane];
            }
            float s = (s0 + s1) + (s2 + s3);
            float hn = omleak * hprev + leak * tanh_fast(s + bc);
            hprev = hn;
            unsigned long long pk =
                ((unsigned long long)(unsigned int)t << 32) |
                (unsigned long long)__float_as_uint(hn);
            // fast: plain store -> local XCD L2 (visible to sc0 loads there)
            __hip_atomic_store(&fbW[c], pk, __ATOMIC_RELAXED,
                               __HIP_MEMORY_SCOPE_WORKGROUP);
            // slow: agent store -> MALL (correct for any WG placement)
            __hip_atomic_store(&sbW[c], pk, __ATOMIC_RELAXED,
                               __HIP_MEMORY_SCOPE_AGENT);
        }

        // prefetch next u quad (latency overlaps the poll)
        if (t < T_STEPS)
            uq = *reinterpret_cast<const float4*>(u + (size_t)t * INPUT + 4 * w);

        // ---- poll my row slice: entry tid = 64w + lane ----
        // Alternate fast(L2)/slow(MALL) tries: fast wins when the %8 XCD
        // mapping holds; slow guarantees progress for any placement.
        // Double buffer (pbW) makes tag-equality deadlock-free: entry e of
        // buffer b is overwritten at t+2 only after every consumer finished
        // its t-poll (publish-dependency chain across WGs).
        unsigned long long v;
        for (;;) {
            v = load_l2(&fbW[tid]);
            if ((unsigned int)(v >> 32) == (unsigned int)t) break;
            v = __hip_atomic_load(&sbW[tid], __ATOMIC_RELAXED,
                                  __HIP_MEMORY_SCOPE_AGENT);
            if ((unsigned int)(v >> 32) == (unsigned int)t) break;
        }
        const float hv = __uint_as_float((unsigned int)v);
        h_slice[w][lane] = hv;           // wave-private; in-wave ds ordering

        // one WG per module writes the coalesced output row (off crit path)
        if (wgi == 0)
            out[(size_t)(t - 1) * (NMOD * UNITS) + modOff + tid] = hv;
    }
}

extern "C" void kernel_launch(void* const* d_in, const int* in_sizes, int n_in,
                              void* d_out, int out_size, void* d_ws, size_t ws_size,
                              hipStream_t stream) {
    const float* u    = (const float*)d_in[0];  // [1, 8192, 64]
    const float* kern = (const float*)d_in[1];  // [4, 64, 1024]
    const float* rec  = (const float*)d_in[2];  // [4, 1024, 1024]
    const float* bias = (const float*)d_in[3];  // [4, 1024]
    float* out = (float*)d_out;                 // [1, 8192, 4096] f32

    unsigned long long* slow = (unsigned long long*)d_ws;              // 64 KB
    unsigned long long* fast = slow + 2 * ENTRIES;                     // 64 KB

    hipLaunchKernelGGL(init_ws_kernel, dim3((WS_ULL + 1023) / 1024), dim3(1024),
                       0, stream, slow);

    void* args[] = { (void*)&u, (void*)&kern, (void*)&rec, (void*)&bias,
                     (void*)&out, (void*)&slow, (void*)&fast };
    hipLaunchCooperativeKernel((const void*)reservoir_persist,
                               dim3(GRID), dim3(WGSIZE), args, 0, stream);
}